// Round 8
// baseline (187.776 us; speedup 1.0000x reference)
//
#include <hip/hip_runtime.h>
#include <math.h>

// Problem constants (fixed by reference: enc (32,64,64,64) fp32, embed (512,64) fp32)
#define DQ 64
#define KQ 512
#define NVEC 131072
#define QOUT_SIZE (NVEC * DQ)              // 8388608
#define LOSS_OFF QOUT_SIZE
#define IDX_OFF (QOUT_SIZE + 1)

#define RPW 64                             // rows per wave (4 MFMA A-tiles) — R20's lever
#define WPB 4                              // waves per block (256 threads)
#define VPB (RPW * WPB)                    // 256 rows per block
#define NBLK (NVEC / VPB)                  // 512 blocks -> 2 rounds of ~1 WG/CU
#define SC 128                             // codes per LDS stage
#define NST (KQ / SC)                      // 4 stages
#define SDQ (SC * DQ)                      // 8192 halfs per stage buffer (16 KB)
// LDS = 2*16KB dbuf + 2KB esq + ~2.5KB misc ~= 35.5 KB -> provable 4 WGs/CU
// -> VGPR budget 512/4 = 128 (R12 rule, confirmed again by R19's 80@36KB).
// Packed-key scheme: esq stored as |e|^2 + 256 so v = esq - 2*dot > 0 always
// (x_sq ~ chi2(64); 256 is 17 sigma -> impossible). Low 9 mantissa bits carry
// the code index. TIE_THR = fp16-product 5.5 sigma + pack noise; validated
// R14/R17/R18/R19 with absmax == R0's (0.0001220703).
#define ESQ_OFF 256.0f
#define TIE_THR 0.09f

typedef __attribute__((ext_vector_type(8))) _Float16 half8;        // 8 f16 = 1 MFMA A/B frag
typedef __attribute__((ext_vector_type(4))) float f32x4;           // MFMA C/D frag

static __device__ __forceinline__ void cvt8h(float4 a, float4 b, half8& h) {
    // RNE f32->f16 (v_cvt_f16_f32 default mode).
    h[0] = (_Float16)a.x; h[1] = (_Float16)a.y; h[2] = (_Float16)a.z; h[3] = (_Float16)a.w;
    h[4] = (_Float16)b.x; h[5] = (_Float16)b.y; h[6] = (_Float16)b.z; h[7] = (_Float16)b.w;
}

// key = distance value with low 9 mantissa bits replaced by the code index.
// Values strictly positive -> IEEE float ordering == bit ordering.
static __device__ __forceinline__ float packk(float v, int code) {
    return __uint_as_float((__float_as_uint(v) & 0xFFFFFE00u) | (unsigned)code);
}

// Init: fp16 codebook in XOR-SWIZZLED layout (chunk c of row k stored at slot
// c ^ (k&7)) so main-kernel ds_read_b128 B-frag reads are conflict-free while
// staging stays a verbatim contiguous copy (conflicts == 0 in R0/R14/R17/R19).
// esq = |e|^2 + 256 (see above).
__global__ void vq_init_kernel(const float* __restrict__ embed,
                               unsigned short* __restrict__ eh,
                               float* __restrict__ esq,
                               float* __restrict__ out) {
    const int t = blockIdx.x * 64 + threadIdx.x;   // 0..4095
    if (t == 0) out[LOSS_OFF] = 0.0f;
    const int k = t >> 3;            // codebook row
    const int c = t & 7;             // 16-byte chunk (8 dims)
    const float4* p = (const float4*)(embed + (size_t)k * DQ + c * 8);
    float4 a = p[0], b = p[1];
    half8 h;
    cvt8h(a, b, h);
    const int slot = c ^ (k & 7);    // XOR swizzle
    *(half8*)(eh + (size_t)k * DQ + slot * 8) = h;

    float ps = 0.f;
    ps = fmaf(a.x, a.x, ps); ps = fmaf(a.y, a.y, ps); ps = fmaf(a.z, a.z, ps); ps = fmaf(a.w, a.w, ps);
    ps = fmaf(b.x, b.x, ps); ps = fmaf(b.y, b.y, ps); ps = fmaf(b.z, b.z, ps); ps = fmaf(b.w, b.w, ps);
    ps += __shfl_xor(ps, 1);
    ps += __shfl_xor(ps, 2);
    ps += __shfl_xor(ps, 4);
    if (c == 0) esq[k] = ps + ESQ_OFF;
}

// R20. 8-round model: per-wave latency is INSENSITIVE to instruction count
// (R0 20.6us @ 384 MFMA == R1 21us @ 128 MFMA) but sensitive to compute-
// density-per-load-wait and VGPR slack (R19: fewer MFMA/ds_read + VGPR 80 ->
// 39us; R16: VGPR 96 -> serialized). Resident waves pinned ~1 WG/CU in all 8
// structures. Total time = (waves/4.3-per-CU) x per-wave-latency. The ONE
// untouched lever: total wave count — RPW was 32 in every round. This round:
// RPW=64 (4 A-tiles/wave) -> 2048 waves (2 dispatch rounds, was 4) AND 2x
// compute per wait-point (16 MFMA per LDP). fp16 is what makes the registers
// fit: A 32 + m1/m2 32 + B 16 + staging 16 + addr ~10 = ~106 < 128 budget
// (bf16 hi/lo would need ~170 -> impossible). SC=128 keeps LDS at 35.5 KB ->
// 4 provable WGs/CU -> budget 128 (R19-confirmed). Single-buffer B frags
// (no Y ping-pong) to hold ~106: the 16-MFMA body gives the compiler ample
// slack to hoist next pair's 4 ds_reads.
// R3 lesson kept: VGPR arrays only indexed by fully-unrolled constants.
__global__ __launch_bounds__(256) void vq_mfma_kernel(const float* __restrict__ enc,
                                                      const float* __restrict__ embed,
                                                      const unsigned short* __restrict__ eh,
                                                      const float* __restrict__ esq,
                                                      float* __restrict__ out) {
    __shared__ unsigned short hs[2 * SDQ];     // fp16 stages (dbuf): 32 KB
    __shared__ float esq_s[KQ];                // 2 KB
    __shared__ int bidx_s[VPB];                // 1 KB
    __shared__ int flag_s[VPB];                // 1 KB
    __shared__ float red[WPB];

    const int tid = threadIdx.x;               // 0..255
    const int lane = tid & 63;
    const int w = tid >> 6;                    // wave 0..3
    const int l15 = lane & 15;
    const int l4 = lane >> 4;                  // 0..3
    const int vb = blockIdx.x * VPB + w * RPW;

    // ---- A loads for 4 tiles, issued FIRST (HBM latency overlaps staging);
    // converted tile-by-tile to keep the float4 live range short. ----
    half8 ahA[4], ahB[4];
#pragma unroll
    for (int a = 0; a < 4; a++) {
        const float* b_ = enc + (size_t)(vb + a * 16 + l15) * DQ + l4 * 8;
        float4 f0 = ((const float4*)b_)[0];
        float4 f1 = ((const float4*)b_)[1];
        float4 f2 = ((const float4*)(b_ + 32))[0];
        float4 f3 = ((const float4*)(b_ + 32))[1];
        cvt8h(f0, f1, ahA[a]);
        cvt8h(f2, f3, ahB[a]);
    }

    // ---- Staging prologue: thread stages 64 B per stage (4 x b128). ----
    half8 r0 = *(const half8*)(eh + tid * 8);
    half8 r1 = *(const half8*)(eh + 2048 + tid * 8);
    half8 r2 = *(const half8*)(eh + 4096 + tid * 8);
    half8 r3 = *(const half8*)(eh + 6144 + tid * 8);
    // write stage 0 into buf 0
    *(half8*)(hs + tid * 8) = r0;        *(half8*)(hs + 2048 + tid * 8) = r1;
    *(half8*)(hs + 4096 + tid * 8) = r2; *(half8*)(hs + 6144 + tid * 8) = r3;
    // prefetch stage 1 into regs
    r0 = *(const half8*)(eh + SDQ + tid * 8);
    r1 = *(const half8*)(eh + SDQ + 2048 + tid * 8);
    r2 = *(const half8*)(eh + SDQ + 4096 + tid * 8);
    r3 = *(const half8*)(eh + SDQ + 6144 + tid * 8);

    esq_s[tid] = esq[tid];
    esq_s[tid + 256] = esq[tid + 256];

    float m1[16], m2[16];
#pragma unroll
    for (int r = 0; r < 16; r++) { m1[r] = 3.0e38f; m2[r] = 3.0e38f; }

    // Swizzled B-frag slot offsets (elements); key = l15&7 (batch*16 == 0 mod 8).
    const int sl0 = (l4 ^ (l15 & 7)) * 8;      // chunk l4     (dims l4*8..+8)
    const int sl1 = sl0 ^ 32;                  // chunk 4+l4   (dims 32+l4*8..+8)

#define LDP(B0, B1, B2, B3, E0, E1, ST, P) { \
    B0 = *(const half8*)(hrow + (2 * (P)) * 1024 + sl0); \
    B1 = *(const half8*)(hrow + (2 * (P)) * 1024 + sl1); \
    B2 = *(const half8*)(hrow + (2 * (P) + 1) * 1024 + sl0); \
    B3 = *(const half8*)(hrow + (2 * (P) + 1) * 1024 + sl1); \
    E0 = esq_s[(ST) * SC + (2 * (P)) * 16 + l15]; \
    E1 = esq_s[(ST) * SC + (2 * (P) + 1) * 16 + l15]; }

// 4 A-tiles x 2 code-batches: 16 MFMA (8 independent 2-deep acc chains) +
// per-tile/r bookkeeping. 2x R0's compute density per LDS wait-point.
#define BODY(ST, P, B0, B1, B2, B3, E0, E1) { \
    const int c0 = (ST) * SC + (2 * (P)) * 16 + l15; \
    _Pragma("unroll") \
    for (int a = 0; a < 4; a++) { \
        f32x4 acc0 = {0.f, 0.f, 0.f, 0.f}; \
        f32x4 acc1 = {0.f, 0.f, 0.f, 0.f}; \
        acc0 = __builtin_amdgcn_mfma_f32_16x16x32_f16(ahA[a], B0, acc0, 0, 0, 0); \
        acc0 = __builtin_amdgcn_mfma_f32_16x16x32_f16(ahB[a], B1, acc0, 0, 0, 0); \
        acc1 = __builtin_amdgcn_mfma_f32_16x16x32_f16(ahA[a], B2, acc1, 0, 0, 0); \
        acc1 = __builtin_amdgcn_mfma_f32_16x16x32_f16(ahB[a], B3, acc1, 0, 0, 0); \
        _Pragma("unroll") \
        for (int r = 0; r < 4; r++) { \
            const int i = a * 4 + r; \
            const float k0 = packk(fmaf(-2.0f, acc0[r], E0), c0); \
            const float k1 = packk(fmaf(-2.0f, acc1[r], E1), c0 + 16); \
            const float mo = m1[i]; \
            m1[i] = fminf(fminf(mo, k0), k1);                          /* v_min3 */ \
            m2[i] = fminf(m2[i], __builtin_amdgcn_fmed3f(mo, k0, k1)); /* 2nd-best */ \
        } \
    } }

    // ---- 4-stage pipeline: barrier / write-next / prefetch+2 / compute.
    for (int st = 0; st < NST; st++) {
        // Drains: LDS writes of buf[st&1] (done last iter) + global loads
        // issued last iter (they had a full stage of compute cover).
        __syncthreads();
        if (st < NST - 1) {                  // write stage st+1 into other buf
            unsigned short* hw = hs + ((st + 1) & 1) * SDQ;
            *(half8*)(hw + tid * 8) = r0;        *(half8*)(hw + 2048 + tid * 8) = r1;
            *(half8*)(hw + 4096 + tid * 8) = r2; *(half8*)(hw + 6144 + tid * 8) = r3;
        }
        if (st < NST - 2) {                  // prefetch stage st+2 (overlaps compute)
            const int o = (st + 2) * SDQ;
            r0 = *(const half8*)(eh + o + tid * 8);
            r1 = *(const half8*)(eh + o + 2048 + tid * 8);
            r2 = *(const half8*)(eh + o + 4096 + tid * 8);
            r3 = *(const half8*)(eh + o + 6144 + tid * 8);
        }
        const unsigned short* hb = hs + (st & 1) * SDQ;
        const unsigned short* hrow = hb + l15 * DQ;    // batch b adds b*1024 elems

        half8 X0, X1, X2, X3;
        float xe0, xe1;
        LDP(X0, X1, X2, X3, xe0, xe1, st, 0)
        BODY(st, 0, X0, X1, X2, X3, xe0, xe1)
        LDP(X0, X1, X2, X3, xe0, xe1, st, 1)
        BODY(st, 1, X0, X1, X2, X3, xe0, xe1)
        LDP(X0, X1, X2, X3, xe0, xe1, st, 2)
        BODY(st, 2, X0, X1, X2, X3, xe0, xe1)
        LDP(X0, X1, X2, X3, xe0, xe1, st, 3)
        BODY(st, 3, X0, X1, X2, X3, xe0, xe1)
    }
#undef LDP
#undef BODY

    // Cross-lane merge over the 16 cols (xor on lane&15 bits). Keys carry the
    // code index -> only 2 shuffles per r.
#pragma unroll
    for (int m = 1; m <= 8; m <<= 1) {
#pragma unroll
        for (int r = 0; r < 16; r++) {
            const float o1 = __shfl_xor(m1[r], m);
            const float o2 = __shfl_xor(m2[r], m);
            m2[r] = fminf(fminf(m2[r], o2), fmaxf(m1[r], o1));
            m1[r] = fminf(m1[r], o1);
        }
    }

    if (l15 == 0) {
#pragma unroll
        for (int a = 0; a < 4; a++)
#pragma unroll
            for (int r = 0; r < 4; r++) {
                const int row = a * 16 + l4 * 4 + r;
                bidx_s[w * RPW + row] = (int)(__float_as_uint(m1[a * 4 + r]) & 511u);
                flag_s[w * RPW + row] = (m2[a * 4 + r] - m1[a * 4 + r] < TIE_THR) ? 1 : 0;
            }
    }
    // bidx_s/flag_s are per-wave segments -> wave-internal visibility only.

    // Exact fp64 rescan of flagged rows (wave-uniform branch; ~1.5% of rows).
    for (int row = 0; row < RPW; row++) {
        if (flag_s[w * RPW + row]) {
            const int v = vb + row;
            const float4* xe = (const float4*)(enc + (size_t)v * DQ);
            unsigned long long best = ~0ULL;
            for (int q = 0; q < 8; q++) {
                const int c = lane * 8 + q;
                const float4* ee = (const float4*)(embed + (size_t)c * DQ);
                double a = 0.0;
                for (int j = 0; j < 16; j++) {          // global ptrs: runtime j fine
                    float4 xx = xe[j], ez = ee[j];
                    double d0 = (double)xx.x - (double)ez.x; a = fma(d0, d0, a);
                    double d1 = (double)xx.y - (double)ez.y; a = fma(d1, d1, a);
                    double d2 = (double)xx.z - (double)ez.z; a = fma(d2, d2, a);
                    double d3 = (double)xx.w - (double)ez.w; a = fma(d3, d3, a);
                }
                unsigned long long pk =
                    (((unsigned long long)__double_as_longlong(a)) & ~511ULL) | (unsigned)c;
                best = (pk < best) ? pk : best;
            }
#pragma unroll
            for (int mm = 1; mm < 64; mm <<= 1) {
                unsigned long long ob = (unsigned long long)__shfl_xor((long long)best, mm);
                best = (ob < best) ? ob : best;
            }
            if (lane == 0) bidx_s[w * RPW + row] = (int)(best & 511ULL);
        }
    }

    // Epilogue: per tile a, lane handles row a*16+l15, chunks l4*8 and
    // 32+l4*8. x recomputed from the fp16 frags (2^-11 rel err; loss-only).
    float lsum = 0.f;
#pragma unroll
    for (int a = 0; a < 4; a++) {
        const int myv = vb + a * 16 + l15;
        const int qb = bidx_s[w * RPW + a * 16 + l15];
        const float* qbase = embed + (size_t)qb * DQ + l4 * 8;
        const float4* qa = (const float4*)qbase;
        const float4* qc = (const float4*)(qbase + 32);
        float4 q0 = qa[0], q1 = qa[1], q2 = qc[0], q3 = qc[1];
        float* obase = out + (size_t)myv * DQ + l4 * 8;
        ((float4*)obase)[0] = q0; ((float4*)obase)[1] = q1;
        ((float4*)(obase + 32))[0] = q2; ((float4*)(obase + 32))[1] = q3;
        if (l4 == 0) out[IDX_OFF + myv] = (float)qb;

        float d;
        d = q0.x - (float)ahA[a][0]; lsum = fmaf(d, d, lsum);
        d = q0.y - (float)ahA[a][1]; lsum = fmaf(d, d, lsum);
        d = q0.z - (float)ahA[a][2]; lsum = fmaf(d, d, lsum);
        d = q0.w - (float)ahA[a][3]; lsum = fmaf(d, d, lsum);
        d = q1.x - (float)ahA[a][4]; lsum = fmaf(d, d, lsum);
        d = q1.y - (float)ahA[a][5]; lsum = fmaf(d, d, lsum);
        d = q1.z - (float)ahA[a][6]; lsum = fmaf(d, d, lsum);
        d = q1.w - (float)ahA[a][7]; lsum = fmaf(d, d, lsum);
        d = q2.x - (float)ahB[a][0]; lsum = fmaf(d, d, lsum);
        d = q2.y - (float)ahB[a][1]; lsum = fmaf(d, d, lsum);
        d = q2.z - (float)ahB[a][2]; lsum = fmaf(d, d, lsum);
        d = q2.w - (float)ahB[a][3]; lsum = fmaf(d, d, lsum);
        d = q3.x - (float)ahB[a][4]; lsum = fmaf(d, d, lsum);
        d = q3.y - (float)ahB[a][5]; lsum = fmaf(d, d, lsum);
        d = q3.z - (float)ahB[a][6]; lsum = fmaf(d, d, lsum);
        d = q3.w - (float)ahB[a][7]; lsum = fmaf(d, d, lsum);
    }

#pragma unroll
    for (int off = 32; off > 0; off >>= 1) lsum += __shfl_down(lsum, off);
    if (lane == 0) red[w] = lsum;
    __syncthreads();
    if (tid == 0) {
        float s = (red[0] + red[1]) + (red[2] + red[3]);
        atomicAdd(out + LOSS_OFF, s * (2.0f / (float)QOUT_SIZE));
    }
}

extern "C" void kernel_launch(void* const* d_in, const int* in_sizes, int n_in,
                              void* d_out, int out_size, void* d_ws, size_t ws_size,
                              hipStream_t stream) {
    const float* enc = (const float*)d_in[0];
    const float* embed = (const float*)d_in[1];
    float* out = (float*)d_out;
    // ws layout: eh[512*64] u16 | esq[512] f32  (~66 KB)
    unsigned short* eh = (unsigned short*)d_ws;
    float* esq = (float*)(eh + KQ * DQ);

    hipLaunchKernelGGL(vq_init_kernel, dim3(64), dim3(64), 0, stream,
                       embed, eh, esq, out);
    hipLaunchKernelGGL(vq_mfma_kernel, dim3(NBLK), dim3(256), 0, stream,
                       enc, embed, eh, esq, out);
}

// Round 9
// 163.395 us; speedup vs baseline: 1.1492x; 1.1492x over previous
//
#include <hip/hip_runtime.h>
#include <math.h>

// Problem constants (fixed by reference: enc (32,64,64,64) fp32, embed (512,64) fp32)
#define DQ 64
#define KQ 512
#define NVEC 131072
#define QOUT_SIZE (NVEC * DQ)              // 8388608
#define LOSS_OFF QOUT_SIZE
#define IDX_OFF (QOUT_SIZE + 1)

#define RPW 32                             // rows per wave (2 MFMA A-tiles)
#define WPB 4                              // waves per block (256 threads)
#define VPB (RPW * WPB)                    // 128 rows per block
#define NBLK (NVEC / VPB)                  // 1024 blocks
#define SC 64                              // codes per LDS stage
#define NST (KQ / SC)                      // 8 stages
#define SDQ (SC * DQ)                      // 4096 shorts per stage buffer
// Packed-key scheme grafted onto R0's bf16 hi/lo shell: esq stored as
// |e|^2 + 256 so v = esq - 2*dot > 0 always (x_sq ~ chi2(64); 256 is 17
// sigma -> impossible). Low 9 mantissa bits of the key carry the code index;
// pack noise <= 511 ulp at v~600 ~ 0.031. hi/lo product err ~3e-4.
// TIE_THR = 0.045 covers both -> exact-fp64 rescan ~0.8% of rows.
#define ESQ_OFF 256.0f
#define TIE_THR 0.045f

typedef __attribute__((ext_vector_type(8))) short short8;          // 8 bf16 = 1 MFMA A/B frag
typedef __attribute__((ext_vector_type(4))) float f32x4;           // MFMA C/D frag

static __device__ __forceinline__ unsigned short f2bf(float f) {   // RNE fp32->bf16
    unsigned u = __float_as_uint(f);
    u += 0x7fff + ((u >> 16) & 1);
    return (unsigned short)(u >> 16);
}
static __device__ __forceinline__ float bf2f(unsigned short h) {
    return __uint_as_float(((unsigned)h) << 16);
}
static __device__ __forceinline__ void cvt8(float4 a, float4 b, short8& hi, short8& lo) {
#define C1(I, V) { unsigned short _h = f2bf(V); hi[I] = (short)_h; lo[I] = (short)f2bf((V) - bf2f(_h)); }
    C1(0, a.x) C1(1, a.y) C1(2, a.z) C1(3, a.w)
    C1(4, b.x) C1(5, b.y) C1(6, b.z) C1(7, b.w)
#undef C1
}

// key = distance value with low 9 mantissa bits replaced by the code index.
// Values strictly positive (ESQ_OFF) -> IEEE float ordering == bit ordering;
// ties resolve to the SMALLEST code (argmin semantics). One v_and_or_b32.
static __device__ __forceinline__ float packk(float v, int code) {
    return __uint_as_float((__float_as_uint(v) & 0xFFFFFE00u) | (unsigned)code);
}

// Init: hi/lo bf16 codebook in XOR-SWIZZLED layout (chunk c of row k stored at
// slot c ^ (k&7)) so main-kernel ds_read_b128 B-frag reads are 2-way max
// (free), while staging stays a verbatim contiguous copy. Plus e_sq(+256) and
// loss=0. Identical to R0's init except the ESQ_OFF shift.
__global__ void vq_init_kernel(const float* __restrict__ embed,
                               unsigned short* __restrict__ ehi,
                               unsigned short* __restrict__ elo,
                               float* __restrict__ esq,
                               float* __restrict__ out) {
    const int t = blockIdx.x * 64 + threadIdx.x;   // 0..4095
    if (t == 0) out[LOSS_OFF] = 0.0f;
    const int k = t >> 3;            // codebook row
    const int c = t & 7;             // 16-byte chunk (8 dims)
    const float4* p = (const float4*)(embed + (size_t)k * DQ + c * 8);
    float4 a = p[0], b = p[1];
    short8 hi, lo;
    cvt8(a, b, hi, lo);
    const int slot = c ^ (k & 7);    // XOR swizzle
    *(short8*)(ehi + (size_t)k * DQ + slot * 8) = hi;
    *(short8*)(elo + (size_t)k * DQ + slot * 8) = lo;

    float ps = 0.f;
    ps = fmaf(a.x, a.x, ps); ps = fmaf(a.y, a.y, ps); ps = fmaf(a.z, a.z, ps); ps = fmaf(a.w, a.w, ps);
    ps = fmaf(b.x, b.x, ps); ps = fmaf(b.y, b.y, ps); ps = fmaf(b.z, b.z, ps); ps = fmaf(b.w, b.w, ps);
    ps += __shfl_xor(ps, 1);
    ps += __shfl_xor(ps, 2);
    ps += __shfl_xor(ps, 4);
    if (c == 0) esq[k] = ps + ESQ_OFF;
}

// R21 (final-candidate). 10-round model: per-wave latency has a ~20.6us/32-row
// floor attained ONLY by this R0-shape (4-wave lockstep, SC=64, 8 stages);
// every restructure raised it (R19 SC=128: 39; R20 RPW=64: 31; R2 barrier-
// free: 55 — residency doubled AND per-wave doubled: shared per-CU resource
// saturates, co-residency buys nothing). Total = 20.6 x 16 waves / 4.3
// resident ~= 77us — R0's measured dur. Work-type counts do NOT move the
// floor (R0 384 MFMA == R1 128 MFMA at 20.6). This round: R0's shell
// byte-identical in structure, plus the one validated micro-opt never tested
// in it — packed-key bookkeeping (no cmp/cndmask, i1[] eliminated: -8 VGPR
// -> more slack under the 128 budget; merge 3->2 shuffles; ~15% less k-loop
// VALU). If dur == 77 again, the stall-floor model is confirmed and this is
// the effective platform floor for this op.
// R3 lesson kept: VGPR arrays only indexed by fully-unrolled constants.
__global__ __launch_bounds__(256) void vq_mfma_kernel(const float* __restrict__ enc,
                                                      const float* __restrict__ embed,
                                                      const unsigned short* __restrict__ ehi,
                                                      const unsigned short* __restrict__ elo,
                                                      const float* __restrict__ esq,
                                                      float* __restrict__ out) {
    __shared__ unsigned short hs[2 * SDQ];     // hi stages (dbuf): 16 KB
    __shared__ unsigned short ls_[2 * SDQ];    // lo stages (dbuf): 16 KB
    __shared__ float esq_s[KQ];                // 2 KB
    __shared__ int bidx_s[VPB];                // 0.5 KB
    __shared__ int flag_s[VPB];                // 0.5 KB
    __shared__ float red[WPB];

    const int tid = threadIdx.x;
    const int lane = tid & 63;
    const int w = tid >> 6;            // wave 0..3
    const int l15 = lane & 15;
    const int l4 = lane >> 4;          // 0..3
    const int vb = blockIdx.x * VPB + w * RPW;

    esq_s[tid] = esq[tid];
    esq_s[tid + 256] = esq[tid + 256];

    // A fragments for 2 tiles: row m = l15 (+a*16), k-chunks l4*8 and 32+l4*8.
    short8 ahA[2], alA[2], ahB[2], alB[2];
#pragma unroll
    for (int a = 0; a < 2; a++) {
        const float* base = enc + (size_t)(vb + a * 16 + l15) * DQ + l4 * 8;
        const float4* p0 = (const float4*)base;
        const float4* p1 = (const float4*)(base + 32);
        cvt8(p0[0], p0[1], ahA[a], alA[a]);
        cvt8(p1[0], p1[1], ahB[a], alB[a]);
    }

    float m1[8], m2[8];
#pragma unroll
    for (int r = 0; r < 8; r++) { m1[r] = 3.4e38f; m2[r] = 3.4e38f; }

    // Swizzled B-frag slot offsets (elements); key = l15&7.
    const int sl0 = (l4 ^ (l15 & 7)) * 8;    // chunk l4     (dims l4*8..+8)
    const int sl1 = sl0 ^ 32;                // chunk 4+l4   (dims 32+l4*8..+8)

    // Staging: thread stages 32 B hi + 32 B lo per stage (two b128 writes each;
    // consecutive 16B groups -> 2-way max = free).
    short8 rh0 = *(const short8*)(ehi + tid * 8);
    short8 rh1 = *(const short8*)(ehi + 2048 + tid * 8);
    short8 rl0 = *(const short8*)(elo + tid * 8);
    short8 rl1 = *(const short8*)(elo + 2048 + tid * 8);
    // write stage 0 into buf 0
    *(short8*)(hs + tid * 8) = rh0;  *(short8*)(hs + 2048 + tid * 8) = rh1;
    *(short8*)(ls_ + tid * 8) = rl0; *(short8*)(ls_ + 2048 + tid * 8) = rl1;
    // prefetch stage 1 into regs
    rh0 = *(const short8*)(ehi + SDQ + tid * 8);
    rh1 = *(const short8*)(ehi + SDQ + 2048 + tid * 8);
    rl0 = *(const short8*)(elo + SDQ + tid * 8);
    rl1 = *(const short8*)(elo + SDQ + 2048 + tid * 8);

#define LDB(H0, H1, L0, L1, S) { const int _o = ((S) * 16 + l15) * DQ; \
    H0 = *(const short8*)(hb + _o + sl0); H1 = *(const short8*)(hb + _o + sl1); \
    L0 = *(const short8*)(lb + _o + sl0); L1 = *(const short8*)(lb + _o + sl1); }

#define BODY(ST, S, BH0, BH1, BL0, BL1) { \
    const int code = (ST) * SC + (S) * 16 + l15; \
    const float ev = esq_s[code]; \
    _Pragma("unroll") \
    for (int a = 0; a < 2; a++) { \
        f32x4 acc = {0.f, 0.f, 0.f, 0.f}; \
        acc = __builtin_amdgcn_mfma_f32_16x16x32_bf16(ahA[a], BH0, acc, 0, 0, 0); \
        acc = __builtin_amdgcn_mfma_f32_16x16x32_bf16(ahB[a], BH1, acc, 0, 0, 0); \
        acc = __builtin_amdgcn_mfma_f32_16x16x32_bf16(alA[a], BH0, acc, 0, 0, 0); \
        acc = __builtin_amdgcn_mfma_f32_16x16x32_bf16(alB[a], BH1, acc, 0, 0, 0); \
        acc = __builtin_amdgcn_mfma_f32_16x16x32_bf16(ahA[a], BL0, acc, 0, 0, 0); \
        acc = __builtin_amdgcn_mfma_f32_16x16x32_bf16(ahB[a], BL1, acc, 0, 0, 0); \
        _Pragma("unroll") \
        for (int r = 0; r < 4; r++) { \
            const int i = a * 4 + r; \
            const float kv = packk(fmaf(-2.0f, acc[r], ev), code); \
            const float mo = m1[i]; \
            m1[i] = fminf(mo, kv); \
            m2[i] = fminf(m2[i], fmaxf(mo, kv)); \
        } \
    } }

    for (int st = 0; st < NST; st++) {
        // Drains: LDS writes of buf[st&1] (done last iter) + global loads
        // issued last iter (they had a full stage of compute cover).
        __syncthreads();
        if (st < NST - 1) {                  // write stage st+1 into other buf
            unsigned short* hw = hs + ((st + 1) & 1) * SDQ;
            unsigned short* lw = ls_ + ((st + 1) & 1) * SDQ;
            *(short8*)(hw + tid * 8) = rh0;  *(short8*)(hw + 2048 + tid * 8) = rh1;
            *(short8*)(lw + tid * 8) = rl0;  *(short8*)(lw + 2048 + tid * 8) = rl1;
        }
        if (st < NST - 2) {                  // prefetch stage st+2 (overlaps compute)
            const int o = (st + 2) * SDQ;
            rh0 = *(const short8*)(ehi + o + tid * 8);
            rh1 = *(const short8*)(ehi + o + 2048 + tid * 8);
            rl0 = *(const short8*)(elo + o + tid * 8);
            rl1 = *(const short8*)(elo + o + 2048 + tid * 8);
        }
        const unsigned short* hb = hs + (st & 1) * SDQ;
        const unsigned short* lb = ls_ + (st & 1) * SDQ;
        // 4 tiles, even/odd B double-buffer in regs (pure LDS->MFMA->VALU)
        short8 b0h0, b0h1, b0l0, b0l1, b1h0, b1h1, b1l0, b1l1;
        LDB(b0h0, b0h1, b0l0, b0l1, 0)
        LDB(b1h0, b1h1, b1l0, b1l1, 1)
        BODY(st, 0, b0h0, b0h1, b0l0, b0l1)
        LDB(b0h0, b0h1, b0l0, b0l1, 2)
        BODY(st, 1, b1h0, b1h1, b1l0, b1l1)
        LDB(b1h0, b1h1, b1l0, b1l1, 3)
        BODY(st, 2, b0h0, b0h1, b0l0, b0l1)
        BODY(st, 3, b1h0, b1h1, b1l0, b1l1)
    }
#undef LDB
#undef BODY

    // Cross-lane merge over the 16 cols (xor on lane&15 bits). Keys carry the
    // code index -> only 2 shuffles per r (was 3 with separate i1).
#pragma unroll
    for (int m = 1; m <= 8; m <<= 1) {
#pragma unroll
        for (int r = 0; r < 8; r++) {
            const float o1 = __shfl_xor(m1[r], m);
            const float o2 = __shfl_xor(m2[r], m);
            m2[r] = fminf(fminf(m2[r], o2), fmaxf(m1[r], o1));
            m1[r] = fminf(m1[r], o1);
        }
    }

    if (l15 == 0) {
#pragma unroll
        for (int a = 0; a < 2; a++)
#pragma unroll
            for (int r = 0; r < 4; r++) {
                const int row = a * 16 + l4 * 4 + r;
                bidx_s[w * RPW + row] = (int)(__float_as_uint(m1[a * 4 + r]) & 511u);
                flag_s[w * RPW + row] = (m2[a * 4 + r] - m1[a * 4 + r] < TIE_THR) ? 1 : 0;
            }
    }
    // bidx_s/flag_s are per-wave segments -> wave-internal visibility only.

    // Exact fp64 rescan of flagged rows (wave-uniform branch; ~0.8% of rows).
    for (int row = 0; row < RPW; row++) {
        if (flag_s[w * RPW + row]) {
            const int v = vb + row;
            const float4* xe = (const float4*)(enc + (size_t)v * DQ);
            unsigned long long best = ~0ULL;
            for (int q = 0; q < 8; q++) {
                const int c = lane * 8 + q;
                const float4* ee = (const float4*)(embed + (size_t)c * DQ);
                double a = 0.0;
                for (int j = 0; j < 16; j++) {          // global ptrs: runtime j fine
                    float4 xx = xe[j], ez = ee[j];
                    double d0 = (double)xx.x - (double)ez.x; a = fma(d0, d0, a);
                    double d1 = (double)xx.y - (double)ez.y; a = fma(d1, d1, a);
                    double d2 = (double)xx.z - (double)ez.z; a = fma(d2, d2, a);
                    double d3 = (double)xx.w - (double)ez.w; a = fma(d3, d3, a);
                }
                unsigned long long p =
                    (((unsigned long long)__double_as_longlong(a)) & ~511ULL) | (unsigned)c;
                best = (p < best) ? p : best;
            }
#pragma unroll
            for (int mm = 1; mm < 64; mm <<= 1) {
                unsigned long long ob = (unsigned long long)__shfl_xor((long long)best, mm);
                best = (ob < best) ? ob : best;
            }
            if (lane == 0) bidx_s[w * RPW + row] = (int)(best & 511ULL);
        }
    }

    // Epilogue: per tile a, lane handles row a*16+l15, chunks l4*8 and 32+l4*8.
    // x recomputed from the hi/lo frags (~1e-5 rel err; loss-only).
    float lsum = 0.f;
#pragma unroll
    for (int a = 0; a < 2; a++) {
        const int myv = vb + a * 16 + l15;
        const int qb = bidx_s[w * RPW + a * 16 + l15];
        const float* qbase = embed + (size_t)qb * DQ + l4 * 8;
        const float4* qa = (const float4*)qbase;
        const float4* qc = (const float4*)(qbase + 32);
        float4 q0 = qa[0], q1 = qa[1], q2 = qc[0], q3 = qc[1];
        float* obase = out + (size_t)myv * DQ + l4 * 8;
        ((float4*)obase)[0] = q0; ((float4*)obase)[1] = q1;
        ((float4*)(obase + 32))[0] = q2; ((float4*)(obase + 32))[1] = q3;
        if (l4 == 0) out[IDX_OFF + myv] = (float)qb;

        float d;
        d = q0.x - (bf2f(ahA[a][0]) + bf2f(alA[a][0])); lsum = fmaf(d, d, lsum);
        d = q0.y - (bf2f(ahA[a][1]) + bf2f(alA[a][1])); lsum = fmaf(d, d, lsum);
        d = q0.z - (bf2f(ahA[a][2]) + bf2f(alA[a][2])); lsum = fmaf(d, d, lsum);
        d = q0.w - (bf2f(ahA[a][3]) + bf2f(alA[a][3])); lsum = fmaf(d, d, lsum);
        d = q1.x - (bf2f(ahA[a][4]) + bf2f(alA[a][4])); lsum = fmaf(d, d, lsum);
        d = q1.y - (bf2f(ahA[a][5]) + bf2f(alA[a][5])); lsum = fmaf(d, d, lsum);
        d = q1.z - (bf2f(ahA[a][6]) + bf2f(alA[a][6])); lsum = fmaf(d, d, lsum);
        d = q1.w - (bf2f(ahA[a][7]) + bf2f(alA[a][7])); lsum = fmaf(d, d, lsum);
        d = q2.x - (bf2f(ahB[a][0]) + bf2f(alB[a][0])); lsum = fmaf(d, d, lsum);
        d = q2.y - (bf2f(ahB[a][1]) + bf2f(alB[a][1])); lsum = fmaf(d, d, lsum);
        d = q2.z - (bf2f(ahB[a][2]) + bf2f(alB[a][2])); lsum = fmaf(d, d, lsum);
        d = q2.w - (bf2f(ahB[a][3]) + bf2f(alB[a][3])); lsum = fmaf(d, d, lsum);
        d = q3.x - (bf2f(ahB[a][4]) + bf2f(alB[a][4])); lsum = fmaf(d, d, lsum);
        d = q3.y - (bf2f(ahB[a][5]) + bf2f(alB[a][5])); lsum = fmaf(d, d, lsum);
        d = q3.z - (bf2f(ahB[a][6]) + bf2f(alB[a][6])); lsum = fmaf(d, d, lsum);
        d = q3.w - (bf2f(ahB[a][7]) + bf2f(alB[a][7])); lsum = fmaf(d, d, lsum);
    }

#pragma unroll
    for (int off = 32; off > 0; off >>= 1) lsum += __shfl_down(lsum, off);
    if (lane == 0) red[w] = lsum;
    __syncthreads();
    if (tid == 0) {
        float s = (red[0] + red[1]) + (red[2] + red[3]);
        atomicAdd(out + LOSS_OFF, s * (2.0f / (float)QOUT_SIZE));
    }
}

extern "C" void kernel_launch(void* const* d_in, const int* in_sizes, int n_in,
                              void* d_out, int out_size, void* d_ws, size_t ws_size,
                              hipStream_t stream) {
    const float* enc = (const float*)d_in[0];
    const float* embed = (const float*)d_in[1];
    float* out = (float*)d_out;
    // ws layout: ehi[512*64] u16 | elo[512*64] u16 | esq[512] f32  (~130 KB)
    unsigned short* ehi = (unsigned short*)d_ws;
    unsigned short* elo = ehi + KQ * DQ;
    float* esq = (float*)(elo + KQ * DQ);

    hipLaunchKernelGGL(vq_init_kernel, dim3(64), dim3(64), 0, stream,
                       embed, ehi, elo, esq, out);
    hipLaunchKernelGGL(vq_mfma_kernel, dim3(NBLK), dim3(256), 0, stream,
                       enc, embed, ehi, elo, esq, out);
}